// Round 9
// baseline (108.314 us; speedup 1.0000x reference)
//
#include <hip/hip_runtime.h>
#include <hip/hip_bf16.h>

// Problem geometry (fixed by the reference)
constexpr int B = 16, K = 100, H = 120, W = 160;
constexpr int HW  = H * W;          // 19200
constexpr int NF4 = HW / 4;         // 4800 float4 per map
constexpr int BK  = B * K;          // 1600 maps per tensor
constexpr int W4  = W / 4;          // 40 float4 per row

// Flat f32 output layout (concatenated in reference return order)
constexpr size_t OFF_DK   = 0;                       // Dk        [B,K,H,W]
constexpr size_t OFF_KP   = (size_t)BK * HW;         // keypoint  [B,3K,3]
constexpr size_t OFF_ZETA = OFF_KP + (size_t)B*3*K*3;// get_zeta  [B,K]
constexpr size_t OFF_TFDK = OFF_ZETA + BK;           // tf_Dk     [B,K,H,W]
constexpr size_t OFF_TFKP = OFF_TFDK + (size_t)BK*HW;// tf_keypoint [B,3K,3]

constexpr int TPB = 256;

typedef float f32x4 __attribute__((ext_vector_type(4)));
typedef float f32x2 __attribute__((ext_vector_type(2)));

// native-rate sigmoid: rcp(1 + exp2(-x*log2e)); identical sequence everywhere
// so recomputed gathers are bit-identical to the stored map values.
__device__ __forceinline__ float fast_sigmoid(float x) {
    const float e = __builtin_amdgcn_exp2f(-1.44269504088896340736f * x);
    return __builtin_amdgcn_rcpf(1.0f + e);
}

// Fused kernel, TWO maps per block (same bk from Rk and tfRk):
//  - grid=1600 -> 6.25 blocks/CU, all resident at t=0 (single generation)
//  - two independent load chains per wave (2x natural MLP, far-apart streams)
//  - index arithmetic shared between the two maps (halved per byte moved)
__global__ __launch_bounds__(TPB)
void fused_kernel(const float* __restrict__ Rk,
                  const float* __restrict__ tfRk,
                  float* __restrict__ out) {
    const int bk = blockIdx.x;

    const f32x4* __restrict__ sa = (const f32x4*)(Rk   + (size_t)bk * HW);
    const f32x4* __restrict__ sb = (const f32x4*)(tfRk + (size_t)bk * HW);
    f32x4* __restrict__ da = (f32x4*)(out + OFF_DK   + (size_t)bk * HW);
    f32x4* __restrict__ db = (f32x4*)(out + OFF_TFDK + (size_t)bk * HW);

    const int tid = threadIdx.x;
    f32x2 sumA = {0,0}, sxA = {0,0}, syA = {0,0};
    f32x2 sumB = {0,0}, sxB = {0,0}, syB = {0,0};

    for (int i = tid; i < NF4; i += TPB) {
        f32x4 va = sa[i];                 // two independent chains in flight
        f32x4 vb = sb[i];

        f32x4 oa, ob;
        oa.x = fast_sigmoid(va.x); oa.y = fast_sigmoid(va.y);
        oa.z = fast_sigmoid(va.z); oa.w = fast_sigmoid(va.w);
        ob.x = fast_sigmoid(vb.x); ob.y = fast_sigmoid(vb.y);
        ob.z = fast_sigmoid(vb.z); ob.w = fast_sigmoid(vb.w);

        da[i] = oa;
        db[i] = ob;

        const int y  = i / W4;
        const int x0 = (i - y * W4) * 4;
        const float fy = (float)y, fx0 = (float)x0;
        const f32x2 yy  = {fy, fy};
        const f32x2 xlo = {fx0,        fx0 + 1.0f};
        const f32x2 xhi = {fx0 + 2.0f, fx0 + 3.0f};

        {
            const f32x2 lo = {oa.x, oa.y}, hi = {oa.z, oa.w};
            const f32x2 rs = lo + hi;
            sumA += rs;
            syA = rs * yy  + syA;
            sxA = lo * xlo + sxA;
            sxA = hi * xhi + sxA;
        }
        {
            const f32x2 lo = {ob.x, ob.y}, hi = {ob.z, ob.w};
            const f32x2 rs = lo + hi;
            sumB += rs;
            syB = rs * yy  + syB;
            sxB = lo * xlo + sxB;
            sxB = hi * xhi + sxB;
        }
    }

    float r[6];
    r[0] = sumA.x + sumA.y;  r[1] = sxA.x + sxA.y;  r[2] = syA.x + syA.y;
    r[3] = sumB.x + sumB.y;  r[4] = sxB.x + sxB.y;  r[5] = syB.x + syB.y;

    // wave (64-lane) reduction of all six partials
    for (int off = 32; off > 0; off >>= 1) {
        #pragma unroll
        for (int j = 0; j < 6; ++j) r[j] += __shfl_down(r[j], off);
    }
    __shared__ float red[6][TPB / 64];
    const int wave = tid >> 6, lane = tid & 63;
    if (lane == 0) {
        #pragma unroll
        for (int j = 0; j < 6; ++j) red[j][wave] = r[j];
    }
    __syncthreads();

    // tid 0 -> main-tensor keypoint row, tid 1 -> tf keypoint row
    if (tid < 2) {
        const int tensor = tid;
        float S = 0, X = 0, Y = 0;
        #pragma unroll
        for (int wv = 0; wv < TPB / 64; ++wv) {
            S += red[3 * tensor + 0][wv];
            X += red[3 * tensor + 1][wv];
            Y += red[3 * tensor + 2][wv];
        }

        const int b = bk / K, k = bk - b * K;
        if (tensor == 0) out[OFF_ZETA + bk] = S;

        const float kx = rintf(X / S);   // RNE matches jnp.round
        const float ky = rintf(Y / S);

        // gathers from the INPUTS, sigmoid recomputed (bit-identical)
        const float* imap  = (tensor ? tfRk : Rk) + (size_t)bk * HW; // s, s1
        const float* imain = Rk + (size_t)bk * HW;                   // s2 (bug-faithful)

        const int gx = (int)kx, gy = (int)ky;
        const float s = fast_sigmoid(imap[gy * W + gx]);

        // mul then add (NOT fma) to match jnp's kp + kp*s, then int32 truncation
        const int kp1x = (int)__fadd_rn(kx, __fmul_rn(kx, s));
        const int kp1y = (int)__fadd_rn(ky, __fmul_rn(ky, s));
        const int kp2x = (int)__fsub_rn(kx, __fmul_rn(kx, s));
        const int kp2y = (int)__fsub_rn(ky, __fmul_rn(ky, s));

        const int w1 = min(max(kp1x, 0), W - 1), h1 = min(max(kp1y, 0), H - 1);
        const int w2 = min(max(kp2x, 0), W - 1), h2 = min(max(kp2y, 0), H - 1);
        const float s1 = fast_sigmoid(imap [h1 * W + w1]);
        const float s2 = fast_sigmoid(imain[h2 * W + w2]);

        float* okp = out + (tensor ? OFF_TFKP : OFF_KP);
        float* r0 = okp + ((size_t)b * 3 * K + k) * 3;
        r0[0] = kx;           r0[1] = ky;           r0[2] = s;
        float* r1 = okp + ((size_t)b * 3 * K + K + k) * 3;
        r1[0] = (float)kp1x;  r1[1] = (float)kp1y;  r1[2] = s1;
        float* r2 = okp + ((size_t)b * 3 * K + 2 * K + k) * 3;
        r2[0] = (float)kp2x;  r2[1] = (float)kp2y;  r2[2] = s2;
    }
}

extern "C" void kernel_launch(void* const* d_in, const int* in_sizes, int n_in,
                              void* d_out, int out_size, void* d_ws, size_t ws_size,
                              hipStream_t stream) {
    const float* Rk   = (const float*)d_in[0];
    const float* tfRk = (const float*)d_in[1];
    float* out = (float*)d_out;

    fused_kernel<<<BK, TPB, 0, stream>>>(Rk, tfRk, out);
}